// Round 1
// baseline (90.839 us; speedup 1.0000x reference)
//
#include <hip/hip_runtime.h>
#include <math.h>

#define NBATCH 128
#define NCONC  6
#define HW     224
#define NPIX   50176   // 224*224
#define NBINS  49
#define NBC    768     // 128*6

__device__ __constant__ float c_P[36] = {
  1.0f, 0.0f, 0.6f, 0.0f, -2.0f, 0.0f,
  0.0f, 1.0f, 0.6f, 0.0f,  0.0f, 0.0f,
  0.1f, 0.1f, 0.5f, 0.0f,  0.0f, 0.0f,
  0.0f, 0.0f, 0.0f, 1.0f,  0.0f, 0.0f,
  0.0f, 0.0f, 0.0f, 0.0f,  1.0f, 0.2f,
  0.0f,-0.6f,-0.6f,-0.6f,  0.6f, 1.0f
};
__device__ __constant__ float c_SIGN[6] = {1.f,-1.f,1.f,-1.f,1.f,1.f};

// ---------------------------------------------------------------------------
// Kernel A: per-(b,c) mean/std -> sigmoid -> 7x7 avg pool -> salient
// one block per (b,c); 256 threads
// ---------------------------------------------------------------------------
__global__ __launch_bounds__(256)
void stats_pool_kernel(const float* __restrict__ x, float* __restrict__ sal) {
  const int bc = blockIdx.x;           // 0..767
  const int t = threadIdx.x;
  const int lane = t & 63;
  const int wave = t >> 6;

  const float* __restrict__ base = x + (size_t)bc * NPIX;
  const float4* __restrict__ xp = (const float4*)base;

  // ---- pass 1: sum / sumsq ----
  float s = 0.f, ss = 0.f;
  #pragma unroll
  for (int k = 0; k < 49; ++k) {
    float4 v = xp[t + k * 256];
    s  += (v.x + v.y) + (v.z + v.w);
    ss += (v.x * v.x + v.y * v.y) + (v.z * v.z + v.w * v.w);
  }
  __shared__ float red[8];
  for (int off = 32; off; off >>= 1) {
    s  += __shfl_down(s, off);
    ss += __shfl_down(ss, off);
  }
  if (lane == 0) { red[wave] = s; red[4 + wave] = ss; }
  __syncthreads();
  const float sum   = red[0] + red[1] + red[2] + red[3];
  const float sumsq = red[4] + red[5] + red[6] + red[7];
  const float mean  = sum * (1.f / (float)NPIX);
  const float var   = (sumsq - sum * mean) * (1.f / (float)(NPIX - 1));
  const float stdv  = sqrtf(var) + 1e-5f;
  const float scale = 2.0f / stdv;           // (x-mean)/std/TAU, TAU=0.5

  // ---- pass 2: sigmoid + 32x32 window means, waves own bins strided ----
  __shared__ float pooled[NBINS];
  for (int bin = wave; bin < NBINS; bin += 4) {
    const int by = bin / 7, bx = bin % 7;
    const float* bp = base + (by * 32) * HW + bx * 32;
    float acc = 0.f;
    #pragma unroll
    for (int j = 0; j < 4; ++j) {
      const int f = lane + 64 * j;     // 0..255
      const int r = f >> 3, c4 = f & 7;
      float4 v = *(const float4*)(bp + r * HW + c4 * 4);
      float e0 = __expf(-(v.x - mean) * scale);
      float e1 = __expf(-(v.y - mean) * scale);
      float e2 = __expf(-(v.z - mean) * scale);
      float e3 = __expf(-(v.w - mean) * scale);
      acc += 1.f / (1.f + e0) + 1.f / (1.f + e1)
           + 1.f / (1.f + e2) + 1.f / (1.f + e3);
    }
    for (int off = 32; off; off >>= 1) acc += __shfl_down(acc, off);
    if (lane == 0) pooled[bin] = acc * (1.f / 1024.f);
  }
  __syncthreads();

  // spatial mean over 49 bins (broadcast LDS reads)
  float sm = 0.f;
  #pragma unroll
  for (int i = 0; i < NBINS; ++i) sm += pooled[i];
  sm *= (1.f / 49.f);

  const int c = bc % 6;
  const float sg = (c == 1 || c == 3) ? -1.f : 1.f;
  if (t < NBINS) {
    float v = sg * (pooled[t] - sm);
    sal[(size_t)bc * NBINS + t] = v > 0.f ? v : 0.f;
  }
}

// ---------------------------------------------------------------------------
// Kernel B: graph message passing + features; one block per batch b
// ---------------------------------------------------------------------------
__global__ __launch_bounds__(256)
void graph_kernel(const float* __restrict__ sal, const float* __restrict__ P_delta,
                  float* __restrict__ gsp, float* __restrict__ feat) {
  const int b = blockIdx.x;
  const int t = threadIdx.x;

  __shared__ float D[NBINS][NBINS];       // 9.4 KB
  __shared__ float P[6][6];
  __shared__ float sl[6][NBINS];
  __shared__ float tmp[6][NBINS];
  __shared__ float g[6][NBINS];

  if (t < 36) {
    P[t / 6][t % 6] = c_P[t] + 0.2f * tanhf(P_delta[t]);
  }
  for (int i = t; i < NBINS * NBINS; i += 256) {
    const int s = i / NBINS, tt = i % NBINS;
    const int ys = s / 7, xs = s % 7, yt = tt / 7, xt = tt % 7;
    const float d2 = (float)((ys - yt) * (ys - yt) + (xs - xt) * (xs - xt));
    D[s][tt] = expf(-d2 * (1.0f / 1.28f));   // 2*sigma^2 = 1.28
  }
  for (int i = t; i < 6 * NBINS; i += 256)
    sl[i / NBINS][i % NBINS] = sal[(size_t)b * 6 * NBINS + i];
  __syncthreads();

  for (int i = t; i < 6 * NBINS; i += 256) {
    const int d = i / NBINS, s = i % NBINS;
    float a = 0.f;
    #pragma unroll
    for (int cc = 0; cc < 6; ++cc) a += P[cc][d] * sl[cc][s];
    tmp[d][s] = a;
  }
  __syncthreads();

  for (int i = t; i < 6 * NBINS; i += 256) {
    const int d = i / NBINS, tt = i % NBINS;
    float a = 0.f;
    #pragma unroll
    for (int s = 0; s < NBINS; ++s) a += tmp[d][s] * D[s][tt];
    a = a > 0.f ? a : 0.f;        // relu
    a *= c_SIGN[d];               // sign flip
    g[d][tt] = a;
    gsp[(size_t)b * 6 * NBINS + i] = a;
  }
  __syncthreads();

  if (t < 6) {
    float mn = g[t][0], mx = g[t][0], sm = 0.f;
    #pragma unroll
    for (int i = 0; i < NBINS; ++i) {
      float v = g[t][i];
      sm += v; mx = fmaxf(mx, v); mn = fminf(mn, v);
    }
    feat[b * 18 + t]      = sm * (1.f / 49.f);
    feat[b * 18 + 6 + t]  = mx;
    feat[b * 18 + 12 + t] = mn;
  }
}

// ---------------------------------------------------------------------------
// Kernel C: bilinear upsample 7x7 -> 224x224 (half-pixel, edge clamp)
// one block per (b,c); fully coalesced float4 stores
// ---------------------------------------------------------------------------
__global__ __launch_bounds__(256)
void upsample_kernel(const float* __restrict__ gsp, float* __restrict__ out) {
  const int bc = blockIdx.x;
  const int t = threadIdx.x;

  __shared__ float g[7][7];
  __shared__ float gy[HW][7];     // y-interpolated rows, 6.1 KB

  if (t < NBINS) g[t / 7][t % 7] = gsp[(size_t)bc * NBINS + t];
  __syncthreads();

  for (int i = t; i < HW * 7; i += 256) {
    const int row = i / 7, xs = i % 7;
    const int y0 = (row >= 16) ? ((row - 16) >> 5) : -1;
    const float fy = (row - 15.5f) * 0.03125f - (float)y0;
    const int y0c = y0 < 0 ? 0 : y0;
    const int y1c = (y0 + 1 > 6) ? 6 : (y0 + 1);
    gy[row][xs] = (1.f - fy) * g[y0c][xs] + fy * g[y1c][xs];
  }
  __syncthreads();

  float4* __restrict__ op = (float4*)(out + (size_t)bc * NPIX);
  #pragma unroll
  for (int k = 0; k < 49; ++k) {
    const int i = t + k * 256;            // 0..12543
    const int row = i / 56, c4 = i % 56;
    const float* gr = &gy[row][0];
    float v[4];
    #pragma unroll
    for (int j = 0; j < 4; ++j) {
      const int xx = c4 * 4 + j;
      const int x0 = (xx >= 16) ? ((xx - 16) >> 5) : -1;
      const float fx = (xx - 15.5f) * 0.03125f - (float)x0;
      const int x0c = x0 < 0 ? 0 : x0;
      const int x1c = (x0 + 1 > 6) ? 6 : (x0 + 1);
      v[j] = (1.f - fx) * gr[x0c] + fx * gr[x1c];
    }
    float4 r; r.x = v[0]; r.y = v[1]; r.z = v[2]; r.w = v[3];
    op[i] = r;
  }
}

// ---------------------------------------------------------------------------
extern "C" void kernel_launch(void* const* d_in, const int* in_sizes, int n_in,
                              void* d_out, int out_size, void* d_ws, size_t ws_size,
                              hipStream_t stream) {
  const float* x       = (const float*)d_in[0];
  const float* P_delta = (const float*)d_in[1];
  float* outp = (float*)d_out;

  float* sal = (float*)d_ws;                 // 768*49 floats
  float* gsp = sal + NBC * NBINS;            // 768*49 floats

  float* feat = outp;                        // (128,18) first
  float* ups  = outp + NBATCH * 18;          // (128,6,224,224) second

  stats_pool_kernel<<<NBC, 256, 0, stream>>>(x, sal);
  graph_kernel<<<NBATCH, 256, 0, stream>>>(sal, P_delta, gsp, feat);
  upsample_kernel<<<NBC, 256, 0, stream>>>(gsp, ups);
}

// Round 2
// 89.901 us; speedup vs baseline: 1.0104x; 1.0104x over previous
//
#include <hip/hip_runtime.h>
#include <math.h>
#include <float.h>

#define HW     224
#define NPIX   50176   // 224*224
#define NBINS  49
#define NBC    768     // 128*6

__device__ __constant__ float c_P[36] = {
  1.0f, 0.0f, 0.6f, 0.0f, -2.0f, 0.0f,
  0.0f, 1.0f, 0.6f, 0.0f,  0.0f, 0.0f,
  0.1f, 0.1f, 0.5f, 0.0f,  0.0f, 0.0f,
  0.0f, 0.0f, 0.0f, 1.0f,  0.0f, 0.0f,
  0.0f, 0.0f, 0.0f, 0.0f,  1.0f, 0.2f,
  0.0f,-0.6f,-0.6f,-0.6f,  0.6f, 1.0f
};

// ---------------------------------------------------------------------------
// Kernel A: per-(b,c) stats + sigmoid + 7x7 pool + salient.
// 448 threads = 7 waves; wave w owns bin-row w (32 rows x 224 cols).
// Entire slice held in registers across the stats barrier -> x read ONCE.
// ---------------------------------------------------------------------------
__global__ __launch_bounds__(448, 1)
void stats_pool_kernel(const float* __restrict__ x, float* __restrict__ sal) {
  const int bc   = blockIdx.x;       // 0..767
  const int t    = threadIdx.x;
  const int lane = t & 63;
  const int w    = t >> 6;           // 0..6 : bin-row (by)
  const int r0   = lane >> 3;        // 0..7
  const int c0   = (lane & 7) << 2;  // 0,4,...,28

  const float* __restrict__ wbase =
      x + (size_t)bc * NPIX + (size_t)(w * 32 + r0) * HW + c0;

  // load: v[j][q] = rows (w*32 + q*8 + r0), cols (j*32 + c0 .. +3)
  float4 v[7][4];
  #pragma unroll
  for (int j = 0; j < 7; ++j)
    #pragma unroll
    for (int q = 0; q < 4; ++q)
      v[j][q] = *(const float4*)(wbase + q * 8 * HW + j * 32);

  // pass 1: sum / sumsq over the whole (b,c) channel
  float s = 0.f, ss = 0.f;
  #pragma unroll
  for (int j = 0; j < 7; ++j)
    #pragma unroll
    for (int q = 0; q < 4; ++q) {
      float4 u = v[j][q];
      s += (u.x + u.y) + (u.z + u.w);
      ss = fmaf(u.x, u.x, fmaf(u.y, u.y, fmaf(u.z, u.z, fmaf(u.w, u.w, ss))));
    }
  #pragma unroll
  for (int off = 32; off; off >>= 1) {
    s  += __shfl_down(s, off);
    ss += __shfl_down(ss, off);
  }
  __shared__ float red[14];
  if (lane == 0) { red[w] = s; red[7 + w] = ss; }
  __syncthreads();
  float sum = 0.f, sumsq = 0.f;
  #pragma unroll
  for (int i = 0; i < 7; ++i) { sum += red[i]; sumsq += red[7 + i]; }
  const float mean  = sum * (1.f / (float)NPIX);
  const float var   = (sumsq - sum * mean) * (1.f / (float)(NPIX - 1));
  const float scale = 2.0f / (sqrtf(var) + 1e-5f);   // /std/TAU, TAU=0.5

  // pass 2: sigmoid + per-bin mean, all from registers
  __shared__ float pooled[NBINS];
  #pragma unroll
  for (int j = 0; j < 7; ++j) {
    float acc = 0.f;
    #pragma unroll
    for (int q = 0; q < 4; ++q) {
      float4 u = v[j][q];
      acc += 1.f / (1.f + __expf((mean - u.x) * scale))
           + 1.f / (1.f + __expf((mean - u.y) * scale))
           + 1.f / (1.f + __expf((mean - u.z) * scale))
           + 1.f / (1.f + __expf((mean - u.w) * scale));
    }
    #pragma unroll
    for (int off = 32; off; off >>= 1) acc += __shfl_down(acc, off);
    if (lane == 0) pooled[w * 7 + j] = acc * (1.f / 1024.f);
  }
  __syncthreads();

  if (t < NBINS) {
    float sm = 0.f;
    #pragma unroll
    for (int i = 0; i < NBINS; ++i) sm += pooled[i];
    sm *= (1.f / 49.f);
    const int c = bc % 6;
    const float sg = (c == 1 || c == 3) ? -1.f : 1.f;
    float val = sg * (pooled[t] - sm);
    sal[(size_t)bc * NBINS + t] = val > 0.f ? val : 0.f;
  }
}

// ---------------------------------------------------------------------------
// Kernel B: graph message passing (separable D) + features + bilinear upsample.
// One block per (b,c=output concept d); 256 threads.
// ---------------------------------------------------------------------------
__global__ __launch_bounds__(256)
void graph_upsample_kernel(const float* __restrict__ sal,
                           const float* __restrict__ P_delta,
                           float* __restrict__ feat, float* __restrict__ out) {
  const int bc = blockIdx.x;
  const int b = bc / 6, d = bc % 6;
  const int t = threadIdx.x;

  __shared__ float sl[6][NBINS];
  __shared__ float ps[6], w7[7];
  __shared__ float tm[7][7], hh[7][7], g[7][7];
  __shared__ float gy[HW][7];

  for (int i = t; i < 6 * NBINS; i += 256)
    sl[i / NBINS][i % NBINS] = sal[(size_t)b * 6 * NBINS + i];
  if (t < 6) ps[t] = c_P[t * 6 + d] + 0.2f * tanhf(P_delta[t * 6 + d]);
  if (t >= 64 && t < 71) {
    const int k = t - 64;
    w7[k] = expf(-(float)(k * k) * (1.0f / 1.28f));   // 2*sigma^2 = 1.28
  }
  __syncthreads();

  // tmp[s] = sum_c sal[c][s] * P[c][d]
  if (t < NBINS) {
    float a = 0.f;
    #pragma unroll
    for (int c = 0; c < 6; ++c) a += sl[c][t] * ps[c];
    tm[t / 7][t % 7] = a;
  }
  __syncthreads();
  // separable D: first contract x-axis
  if (t < NBINS) {
    const int ys = t / 7, xt = t % 7;
    float a = 0.f;
    #pragma unroll
    for (int xs = 0; xs < 7; ++xs) a += tm[ys][xs] * w7[xs > xt ? xs - xt : xt - xs];
    hh[ys][xt] = a;
  }
  __syncthreads();
  const float sg = (d == 1 || d == 3) ? -1.f : 1.f;
  if (t < NBINS) {
    const int yt = t / 7, xt = t % 7;
    float a = 0.f;
    #pragma unroll
    for (int ys = 0; ys < 7; ++ys) a += hh[ys][xt] * w7[ys > yt ? ys - yt : yt - ys];
    a = a > 0.f ? a : 0.f;    // relu
    g[yt][xt] = a * sg;       // sign flip
  }
  __syncthreads();

  // features (wave 0): mean/max/min over the 49 g values
  if (t < 64) {
    const float vv = (t < NBINS) ? g[t / 7][t % 7] : 0.f;
    float vs = (t < NBINS) ? vv : 0.f;
    float vmx = (t < NBINS) ? vv : -FLT_MAX;
    float vmn = (t < NBINS) ? vv : FLT_MAX;
    #pragma unroll
    for (int off = 32; off; off >>= 1) {
      vs += __shfl_down(vs, off);
      vmx = fmaxf(vmx, __shfl_down(vmx, off));
      vmn = fminf(vmn, __shfl_down(vmn, off));
    }
    if (t == 0) {
      feat[b * 18 + d]      = vs * (1.f / 49.f);
      feat[b * 18 + 6 + d]  = vmx;
      feat[b * 18 + 12 + d] = vmn;
    }
  }

  // bilinear upsample: y-interp into LDS, then coalesced float4 stores
  for (int i = t; i < HW * 7; i += 256) {
    const int row = i / 7, xs = i % 7;
    const int y0 = (row >= 16) ? ((row - 16) >> 5) : -1;
    const float fy = (row - 15.5f) * 0.03125f - (float)y0;
    const int y0c = y0 < 0 ? 0 : y0;
    const int y1c = (y0 + 1 > 6) ? 6 : (y0 + 1);
    gy[row][xs] = (1.f - fy) * g[y0c][xs] + fy * g[y1c][xs];
  }
  __syncthreads();

  float4* __restrict__ op = (float4*)(out + (size_t)bc * NPIX);
  #pragma unroll
  for (int k = 0; k < 49; ++k) {
    const int i = t + k * 256;           // 0..12543
    const int row = i / 56, c4 = i % 56;
    const float* gr = &gy[row][0];
    float vv[4];
    #pragma unroll
    for (int jj = 0; jj < 4; ++jj) {
      const int xx = c4 * 4 + jj;
      const int x0 = (xx >= 16) ? ((xx - 16) >> 5) : -1;
      const float fx = (xx - 15.5f) * 0.03125f - (float)x0;
      const int x0c = x0 < 0 ? 0 : x0;
      const int x1c = (x0 + 1 > 6) ? 6 : (x0 + 1);
      vv[jj] = (1.f - fx) * gr[x0c] + fx * gr[x1c];
    }
    op[i] = make_float4(vv[0], vv[1], vv[2], vv[3]);
  }
}

// ---------------------------------------------------------------------------
extern "C" void kernel_launch(void* const* d_in, const int* in_sizes, int n_in,
                              void* d_out, int out_size, void* d_ws, size_t ws_size,
                              hipStream_t stream) {
  const float* x       = (const float*)d_in[0];
  const float* P_delta = (const float*)d_in[1];
  float* outp = (float*)d_out;

  float* sal = (float*)d_ws;                 // 768*49 floats

  float* feat = outp;                        // (128,18) first
  float* ups  = outp + 128 * 18;             // (128,6,224,224) second

  stats_pool_kernel<<<NBC, 448, 0, stream>>>(x, sal);
  graph_upsample_kernel<<<NBC, 256, 0, stream>>>(sal, P_delta, feat, ups);
}

// Round 3
// 83.835 us; speedup vs baseline: 1.0835x; 1.0724x over previous
//
#include <hip/hip_runtime.h>
#include <math.h>
#include <float.h>

#define HW      224
#define NPIX    50176      // 224*224
#define NBINS   49
#define NBC     768        // 128*6
#define NSTRIPE 7
#define STRIPEF 7168       // 32*224 floats per stripe

__device__ __constant__ float c_P[36] = {
  1.0f, 0.0f, 0.6f, 0.0f, -2.0f, 0.0f,
  0.0f, 1.0f, 0.6f, 0.0f,  0.0f, 0.0f,
  0.1f, 0.1f, 0.5f, 0.0f,  0.0f, 0.0f,
  0.0f, 0.0f, 0.0f, 1.0f,  0.0f, 0.0f,
  0.0f, 0.0f, 0.0f, 0.0f,  1.0f, 0.2f,
  0.0f,-0.6f,-0.6f,-0.6f,  0.6f, 1.0f
};

// ---------------------------------------------------------------------------
// K1: per-(b,c,stripe) partial sum/sumsq. 5376 blocks x 256 thr.
// Stripe = 32 contiguous rows (28 KB), 7 float4 per thread, coalesced.
// ---------------------------------------------------------------------------
__global__ __launch_bounds__(256)
void stats_partial_kernel(const float* __restrict__ x, float* __restrict__ part) {
  const int bid = blockIdx.x;                 // bc*7 + stripe
  const int t = threadIdx.x;
  const float4* __restrict__ p = (const float4*)(x + (size_t)bid * STRIPEF);

  float s = 0.f, ss = 0.f;
  #pragma unroll
  for (int k = 0; k < 7; ++k) {
    float4 u = p[t + k * 256];
    s += (u.x + u.y) + (u.z + u.w);
    ss = fmaf(u.x, u.x, fmaf(u.y, u.y, fmaf(u.z, u.z, fmaf(u.w, u.w, ss))));
  }
  #pragma unroll
  for (int off = 32; off; off >>= 1) {
    s  += __shfl_down(s, off);
    ss += __shfl_down(ss, off);
  }
  __shared__ float red[8];
  const int lane = t & 63, w = t >> 6;
  if (lane == 0) { red[w] = s; red[4 + w] = ss; }
  __syncthreads();
  if (t == 0) part[bid * 2]     = red[0] + red[1] + red[2] + red[3];
  if (t == 1) part[bid * 2 + 1] = red[4] + red[5] + red[6] + red[7];
}

// ---------------------------------------------------------------------------
// K2: finish stats, sigmoid, 32x32 window means for one stripe (7 windows).
// 5376 blocks x 256 thr; thread (r=t>>3, c=t&7) does one float4 per window.
// ---------------------------------------------------------------------------
__global__ __launch_bounds__(256)
void pool_kernel(const float* __restrict__ x, const float* __restrict__ part,
                 float* __restrict__ pooled) {
  const int bid = blockIdx.x;                 // bc*7 + binrow
  const int bc = bid / 7;
  const int binrow = bid - bc * 7;
  const int t = threadIdx.x;

  __shared__ float stat[2];
  if (t < 2) {
    float a = 0.f;
    #pragma unroll
    for (int i = 0; i < 7; ++i) a += part[(bc * 7 + i) * 2 + t];
    stat[t] = a;
  }
  __syncthreads();
  const float mean  = stat[0] * (1.f / (float)NPIX);
  const float var   = (stat[1] - stat[0] * mean) * (1.f / (float)(NPIX - 1));
  const float scale = 2.0f / (sqrtf(var) + 1e-5f);   // /std/TAU, TAU=0.5

  const int r = t >> 3, c = t & 7;
  const float4* __restrict__ p = (const float4*)(x + (size_t)bid * STRIPEF);

  float sv[7];
  #pragma unroll
  for (int j = 0; j < 7; ++j) {
    float4 u = p[r * 56 + j * 8 + c];
    sv[j] = 1.f / (1.f + __expf((mean - u.x) * scale))
          + 1.f / (1.f + __expf((mean - u.y) * scale))
          + 1.f / (1.f + __expf((mean - u.z) * scale))
          + 1.f / (1.f + __expf((mean - u.w) * scale));
  }
  #pragma unroll
  for (int j = 0; j < 7; ++j) {
    float a = sv[j];
    #pragma unroll
    for (int off = 32; off; off >>= 1) a += __shfl_down(a, off);
    sv[j] = a;
  }
  __shared__ float red[4][7];
  const int lane = t & 63, w = t >> 6;
  if (lane == 0) {
    #pragma unroll
    for (int j = 0; j < 7; ++j) red[w][j] = sv[j];
  }
  __syncthreads();
  if (t < 7)
    pooled[bc * NBINS + binrow * 7 + t] =
        (red[0][t] + red[1][t] + red[2][t] + red[3][t]) * (1.f / 1024.f);
}

// ---------------------------------------------------------------------------
// K3: salient + graph message passing (separable D) + features + upsample.
// One block per (b, d); 256 threads.
// ---------------------------------------------------------------------------
__global__ __launch_bounds__(256)
void graph_upsample_kernel(const float* __restrict__ pooled,
                           const float* __restrict__ P_delta,
                           float* __restrict__ feat, float* __restrict__ out) {
  const int bc = blockIdx.x;
  const int b = bc / 6, d = bc % 6;
  const int t = threadIdx.x;

  __shared__ float pl[6][NBINS];
  __shared__ float chm[6];
  __shared__ float ps[6], w7[7];
  __shared__ float tm[7][7], hh[7][7], g[7][7];
  __shared__ float gy[HW][7];

  for (int i = t; i < 6 * NBINS; i += 256)
    pl[i / NBINS][i % NBINS] = pooled[(size_t)b * 6 * NBINS + i];
  if (t < 6) ps[t] = c_P[t * 6 + d] + 0.2f * tanhf(P_delta[t * 6 + d]);
  if (t >= 64 && t < 71) {
    const int k = t - 64;
    w7[k] = expf(-(float)(k * k) * (1.0f / 1.28f));   // 2*sigma^2 = 1.28
  }
  __syncthreads();

  if (t < 6) {
    float a = 0.f;
    #pragma unroll
    for (int i = 0; i < NBINS; ++i) a += pl[t][i];
    chm[t] = a * (1.f / 49.f);
  }
  __syncthreads();
  // salient in place: relu(sign_c * (pooled - mean))
  for (int i = t; i < 6 * NBINS; i += 256) {
    const int c = i / NBINS, s = i % NBINS;
    const float sgc = (c == 1 || c == 3) ? -1.f : 1.f;
    float v = sgc * (pl[c][s] - chm[c]);
    pl[c][s] = v > 0.f ? v : 0.f;
  }
  __syncthreads();

  // tmp[s] = sum_c sal[c][s] * P[c][d]
  if (t < NBINS) {
    float a = 0.f;
    #pragma unroll
    for (int c = 0; c < 6; ++c) a += pl[c][t] * ps[c];
    tm[t / 7][t % 7] = a;
  }
  __syncthreads();
  if (t < NBINS) {
    const int ys = t / 7, xt = t % 7;
    float a = 0.f;
    #pragma unroll
    for (int xs = 0; xs < 7; ++xs) a += tm[ys][xs] * w7[xs > xt ? xs - xt : xt - xs];
    hh[ys][xt] = a;
  }
  __syncthreads();
  const float sg = (d == 1 || d == 3) ? -1.f : 1.f;
  if (t < NBINS) {
    const int yt = t / 7, xt = t % 7;
    float a = 0.f;
    #pragma unroll
    for (int ys = 0; ys < 7; ++ys) a += hh[ys][xt] * w7[ys > yt ? ys - yt : yt - ys];
    a = a > 0.f ? a : 0.f;    // relu
    g[yt][xt] = a * sg;       // sign flip
  }
  __syncthreads();

  if (t < 64) {
    const float vv = (t < NBINS) ? g[t / 7][t % 7] : 0.f;
    float vs  = (t < NBINS) ? vv : 0.f;
    float vmx = (t < NBINS) ? vv : -FLT_MAX;
    float vmn = (t < NBINS) ? vv : FLT_MAX;
    #pragma unroll
    for (int off = 32; off; off >>= 1) {
      vs += __shfl_down(vs, off);
      vmx = fmaxf(vmx, __shfl_down(vmx, off));
      vmn = fminf(vmn, __shfl_down(vmn, off));
    }
    if (t == 0) {
      feat[b * 18 + d]      = vs * (1.f / 49.f);
      feat[b * 18 + 6 + d]  = vmx;
      feat[b * 18 + 12 + d] = vmn;
    }
  }

  for (int i = t; i < HW * 7; i += 256) {
    const int row = i / 7, xs = i % 7;
    const int y0 = (row >= 16) ? ((row - 16) >> 5) : -1;
    const float fy = (row - 15.5f) * 0.03125f - (float)y0;
    const int y0c = y0 < 0 ? 0 : y0;
    const int y1c = (y0 + 1 > 6) ? 6 : (y0 + 1);
    gy[row][xs] = (1.f - fy) * g[y0c][xs] + fy * g[y1c][xs];
  }
  __syncthreads();

  float4* __restrict__ op = (float4*)(out + (size_t)bc * NPIX);
  #pragma unroll
  for (int k = 0; k < 49; ++k) {
    const int i = t + k * 256;           // 0..12543
    const int row = i / 56, c4 = i % 56;
    const float* gr = &gy[row][0];
    float vv[4];
    #pragma unroll
    for (int jj = 0; jj < 4; ++jj) {
      const int xx = c4 * 4 + jj;
      const int x0 = (xx >= 16) ? ((xx - 16) >> 5) : -1;
      const float fx = (xx - 15.5f) * 0.03125f - (float)x0;
      const int x0c = x0 < 0 ? 0 : x0;
      const int x1c = (x0 + 1 > 6) ? 6 : (x0 + 1);
      vv[jj] = (1.f - fx) * gr[x0c] + fx * gr[x1c];
    }
    op[i] = make_float4(vv[0], vv[1], vv[2], vv[3]);
  }
}

// ---------------------------------------------------------------------------
extern "C" void kernel_launch(void* const* d_in, const int* in_sizes, int n_in,
                              void* d_out, int out_size, void* d_ws, size_t ws_size,
                              hipStream_t stream) {
  const float* x       = (const float*)d_in[0];
  const float* P_delta = (const float*)d_in[1];
  float* outp = (float*)d_out;

  float* part   = (float*)d_ws;                    // 5376*2 floats
  float* pooled = part + NBC * NSTRIPE * 2;        // 768*49 floats

  float* feat = outp;                              // (128,18)
  float* ups  = outp + 128 * 18;                   // (128,6,224,224)

  stats_partial_kernel<<<NBC * NSTRIPE, 256, 0, stream>>>(x, part);
  pool_kernel<<<NBC * NSTRIPE, 256, 0, stream>>>(x, part, pooled);
  graph_upsample_kernel<<<NBC, 256, 0, stream>>>(pooled, P_delta, feat, ups);
}